// Round 2
// baseline (178.321 us; speedup 1.0000x reference)
//
#include <hip/hip_runtime.h>
#include <stdint.h>

// GAE backward scan. B=4096 rows, T=2048 steps.
// R3: persistent-block DMA pipeline. Grid = 1024 blocks x 4 rows.
// Each row's 4 input arrays are staged into LDS with
// global_load_lds (width 16) -> zero VGPR cost, regs stay <=64,
// all 1024 blocks co-resident (4 blocks/CU, 33 KB LDS each).
// Staging is WAVE-PRIVATE (each wave DMAs its own lane-linear 1 KB
// segment and reads only that segment) -> no barrier for staging.
// Row k+1's DMA is issued before row k's scan, so HBM latency hides
// under the scan/barrier phase; steady-state wait is a counted
// s_waitcnt vmcnt(2) (lets the previous row's 2 nontemporal stores
// stay in flight). The affine-combine barrier is a raw s_barrier +
// lgkmcnt(0) so it does NOT drain the in-flight DMA (unlike
// __syncthreads, which emits vmcnt(0)).

constexpr float GAMMA = 0.99f;
constexpr float LMBDA = 0.95f;
constexpr int   T     = 2048;
constexpr int   TPB   = 512;
constexpr int   E     = T / TPB;        // 4 elements per thread
constexpr int   NW    = TPB / 64;       // 8 waves per block
constexpr int   RPB   = 4;              // rows per block (grid = B/RPB)

typedef float f4 __attribute__((ext_vector_type(4)));

typedef __attribute__((address_space(1))) void  as1_void;
typedef __attribute__((address_space(3))) void  as3_void;

__device__ __forceinline__ void stage16(const void* g, void* s) {
    __builtin_amdgcn_global_load_lds((as1_void*)g, (as3_void*)s, 16, 0, 0);
}

__global__ __launch_bounds__(TPB, 8) void gae_kernel(
    const float* __restrict__ reward,
    const int*   __restrict__ term,
    const float* __restrict__ value,
    const float* __restrict__ next_value,
    float* __restrict__ adv_out,
    float* __restrict__ ret_out)
{
    const int j    = threadIdx.x;
    const int wave = j >> 6;
    const int lane = j & 63;

    __shared__ float sRew[T];
    __shared__ int   sTrm[T];
    __shared__ float sVal[T];
    __shared__ float sNxt[T];
    __shared__ float sAf[2][NW];
    __shared__ float sBf[2][NW];

    // This thread's element offset within row 0 of this block's 4-row span.
    const size_t tbase = (size_t)blockIdx.x * (RPB * T) + (size_t)j * E;
    const int    wofs  = wave << 8;     // wave's 256-float LDS segment

    // Prologue: DMA row 0 into LDS, drain fully (loop's vmcnt(2) is
    // only valid once the 2-newest-ops are stores).
    stage16(reward     + tbase, sRew + wofs);
    stage16(term       + tbase, sTrm + wofs);
    stage16(value      + tbase, sVal + wofs);
    stage16(next_value + tbase, sNxt + wofs);
    asm volatile("s_waitcnt vmcnt(0)" ::: "memory");

    #pragma unroll 1
    for (int k = 0; k < RPB; ++k) {
        // Wait this wave's 4 staging loads of row k; the 2 newest vmem
        // ops (row k-1's nontemporal stores) may stay in flight.
        asm volatile("s_waitcnt vmcnt(2)" ::: "memory");

        const f4   rv = *(const f4*  )(sRew + j * E);
        const int4 tv = *(const int4*)(sTrm + j * E);
        const f4   vv = *(const f4*  )(sVal + j * E);
        const f4   nx = *(const f4*  )(sNxt + j * E);

        // ds_reads must land before the DMA overwrites the buffer
        // (lgkm vs vm queues are unordered).
        asm volatile("s_waitcnt lgkmcnt(0)" ::: "memory");
        if (k + 1 < RPB) {
            const size_t nb = tbase + (size_t)(k + 1) * T;
            stage16(reward     + nb, sRew + wofs);
            stage16(term       + nb, sTrm + wofs);
            stage16(value      + nb, sVal + wofs);
            stage16(next_value + nb, sNxt + wofs);
        }
        asm volatile("" ::: "memory");

        const float r [E] = {rv[0], rv[1], rv[2], rv[3]};
        const float nd[E] = {1.f - (float)tv.x, 1.f - (float)tv.y,
                             1.f - (float)tv.z, 1.f - (float)tv.w};
        const float v [E] = {vv[0], vv[1], vv[2], vv[3]};
        const float nxv[E]= {nx[0], nx[1], nx[2], nx[3]};

        // Intra-thread backward scan, zero carry. loc[t] = local gae,
        // P[t] = product of decay c over [t..E-1].
        float loc[E], P[E];
        {
            float g = 0.f, p = 1.f;
            #pragma unroll
            for (int t = E - 1; t >= 0; --t) {
                const float c     = (GAMMA * LMBDA) * nd[t];
                const float delta = fmaf(GAMMA * nxv[t], nd[t], r[t]) - v[t];
                g = fmaf(c, g, delta);
                p *= c;
                loc[t] = g;
                P[t]   = p;
            }
        }

        // Per-wave inclusive suffix-composition scan of (A,B)=(loc[0],P[0]).
        float A = loc[0], Bc = P[0];
        #pragma unroll
        for (int off = 1; off < 64; off <<= 1) {
            const float a2 = __shfl_down(A,  off, 64);
            const float b2 = __shfl_down(Bc, off, 64);
            if (lane + off < 64) {
                A  = fmaf(Bc, a2, A);
                Bc *= b2;
            }
        }

        // Publish wave affine; ping-pong buffer by row parity so one
        // barrier per row suffices (WAR separated by next row's barrier).
        const int pb = k & 1;
        if (lane == 0) { sAf[pb][wave] = A; sBf[pb][wave] = Bc; }

        // Exclusive suffix within the wave (from lane+1); lane 63 = identity.
        float eA = __shfl_down(A,  1, 64);
        float eB = __shfl_down(Bc, 1, 64);
        if (lane == 63) { eA = 0.f; eB = 1.f; }

        // Raw barrier: drain only LDS ops, keep the row-(k+1) DMA in flight.
        asm volatile("s_waitcnt lgkmcnt(0)" ::: "memory");
        __builtin_amdgcn_s_barrier();
        asm volatile("" ::: "memory");

        // Carry entering this wave = composition of wave-affines to the right.
        float wcarry = 0.f;
        #pragma unroll
        for (int w = NW - 1; w > 0; --w) {
            if (w > wave) wcarry = fmaf(sBf[pb][w], wcarry, sAf[pb][w]);
        }

        // Carry entering this thread's chunk.
        const float gin = fmaf(eB, wcarry, eA);

        f4 a4, q4;
        #pragma unroll
        for (int t = 0; t < E; ++t) {
            const float a = fmaf(P[t], gin, loc[t]);
            a4[t] = a;
            q4[t] = a + v[t];
        }
        const size_t gb = tbase + (size_t)k * T;
        __builtin_nontemporal_store(a4, (f4*)(adv_out + gb));
        __builtin_nontemporal_store(q4, (f4*)(ret_out + gb));
    }
}

extern "C" void kernel_launch(void* const* d_in, const int* in_sizes, int n_in,
                              void* d_out, int out_size, void* d_ws, size_t ws_size,
                              hipStream_t stream) {
    const float* reward     = (const float*)d_in[0];
    const int*   term       = (const int*  )d_in[1];
    const float* value      = (const float*)d_in[2];
    const float* next_value = (const float*)d_in[3];

    const int BT = in_sizes[0];
    const int B  = BT / T;

    float* adv = (float*)d_out;
    float* ret = adv + BT;

    gae_kernel<<<B / RPB, TPB, 0, stream>>>(reward, term, value, next_value, adv, ret);
}